// Round 16
// baseline (135.934 us; speedup 1.0000x reference)
//
#include <hip/hip_runtime.h>
#include <hip/hip_bf16.h>

typedef __attribute__((ext_vector_type(8))) short bf16x8;
typedef __attribute__((ext_vector_type(4))) float f32x4;
typedef __attribute__((ext_vector_type(16))) float f32x16;
typedef __attribute__((ext_vector_type(4))) unsigned short u16x4;
typedef __attribute__((ext_vector_type(4))) unsigned int u32x4;

#define NB 2
#define NS 4096
#define ND 512
#define NH 8

__device__ __forceinline__ unsigned short f2bf(float f) {
  unsigned int u = __float_as_uint(f);
  u += 0x7fffu + ((u >> 16) & 1u);
  return (unsigned short)(u >> 16);
}

__device__ __forceinline__ float exp2_hw(float x) {
  float r;
  asm("v_exp_f32 %0, %1" : "=v"(r) : "v"(x));
  return r;
}

__device__ __forceinline__ unsigned cvtpk(float lo, float hi) {
  unsigned r;
  asm("v_cvt_pk_bf16_f32 %0, %1, %2" : "=v"(r) : "v"(lo), "v"(hi));
  return r;
}

__device__ __forceinline__ void swap32(unsigned& a, unsigned& b) {
  asm("v_permlane32_swap_b32 %0, %1" : "+v"(a), "+v"(b));
}

__device__ __forceinline__ bf16x8 mkfrag(unsigned w0, unsigned w1,
                                         unsigned w2, unsigned w3) {
  u32x4 u = {w0, w1, w2, w3};
  return __builtin_bit_cast(bf16x8, u);
}

// async global->LDS DMA, 16B per lane; dest = wave-uniform base + lane*16
__device__ __forceinline__ void gload_lds16(const unsigned short* g,
                                            unsigned short* l) {
  __builtin_amdgcn_global_load_lds(
      (const __attribute__((address_space(1))) unsigned int*)g,
      (__attribute__((address_space(3))) unsigned int*)l, 16, 0, 0);
}

// ---------------- pack: fp32 -> bf16, pre-transpose weights ----------------
__global__ void pack_kernel(const float* __restrict__ x,
                            const float* __restrict__ Wq,
                            const float* __restrict__ Wk,
                            const float* __restrict__ Wv,
                            const float* __restrict__ Wo,
                            unsigned short* __restrict__ x_bf,
                            unsigned short* __restrict__ w3,    // [3*512][512]
                            unsigned short* __restrict__ wo_t)  // [512][512]
{
  int idx = blockIdx.x * 256 + threadIdx.x;
  const int NX4 = NB * NS * ND / 4;  // 1048576 float4s
  const int NW = 512 * 512;          // 262144
  if (idx < NX4) {
    const float4 f = ((const float4*)x)[idx];
    u16x4 o;
    o[0] = f2bf(f.x); o[1] = f2bf(f.y); o[2] = f2bf(f.z); o[3] = f2bf(f.w);
    ((u16x4*)x_bf)[idx] = o;
  } else if (idx < NX4 + 3 * NW) {
    int j = idx - NX4;
    int p = j / NW;
    int r = j - p * NW;
    int n = r >> 9, d = r & 511;
    int h = n >> 6, o = n & 63;
    const float* W = (p == 0) ? Wq : (p == 1) ? Wk : Wv;
    w3[j] = f2bf(W[(h * 512 + d) * 64 + o]);
  } else if (idx < NX4 + 4 * NW) {
    int j = idx - NX4 - 3 * NW;
    int n = j >> 9, kk = j & 511;
    wo_t[j] = f2bf(Wo[kk * 512 + n]);
  }
}

// ---- GEMM v2: C[m][n] = sum_k A[m][k]*Bm[n][k], K=512, DMA-staged dbuf ----
template <int MODE>
__global__ __launch_bounds__(256, 2) void gemm_bt(
    const unsigned short* __restrict__ A,
    const unsigned short* __restrict__ Bm,
    const float* __restrict__ b0,
    const float* __restrict__ b1,
    const float* __restrict__ b2,
    unsigned short* __restrict__ qo,
    unsigned short* __restrict__ ko,
    unsigned short* __restrict__ vo,
    float* __restrict__ fo) {
  __shared__ unsigned short Al[2][128 * 32];
  __shared__ unsigned short Bl[2][128 * 32];
  const int t = threadIdx.x;
  const int m0 = blockIdx.x * 128;
  const int n0 = blockIdx.y * 128;
  const int lane = t & 63;
  const int w = t >> 6;
  const int wm = w >> 1, wn = w & 1;
  const int c = lane & 15, g = lane >> 4;

  f32x4 acc[4][4];
#pragma unroll
  for (int i = 0; i < 4; ++i)
#pragma unroll
    for (int j = 0; j < 4; ++j) acc[i][j] = (f32x4){0.f, 0.f, 0.f, 0.f};

  const int rr = lane >> 2;
  const int kc = (lane & 3) * 8;
  const unsigned short* Ab = A + (size_t)(m0 + w * 32 + rr) * 512 + kc;
  const unsigned short* Bb = Bm + (size_t)(n0 + w * 32 + rr) * 512 + kc;

  auto ISSUE = [&](int ks, int bi) {
    const int k0 = ks * 32;
    gload_lds16(Ab + k0, &Al[bi][w * 1024]);
    gload_lds16(Ab + 16 * 512 + k0, &Al[bi][w * 1024 + 512]);
    gload_lds16(Bb + k0, &Bl[bi][w * 1024]);
    gload_lds16(Bb + 16 * 512 + k0, &Bl[bi][w * 1024 + 512]);
  };

  ISSUE(0, 0);
  for (int ks = 0; ks < 16; ++ks) {
    const int cur = ks & 1;
    asm volatile("s_waitcnt vmcnt(0)" ::: "memory");
    __builtin_amdgcn_s_barrier();
    __builtin_amdgcn_sched_barrier(0);
    if (ks + 1 < 16) ISSUE(ks + 1, cur ^ 1);  // buf^1 readers done (barrier)

    bf16x8 af[4], bfr[4];
#pragma unroll
    for (int mf = 0; mf < 4; ++mf)
      af[mf] = *(const bf16x8*)&Al[cur][(wm * 64 + mf * 16 + c) * 32 + g * 8];
#pragma unroll
    for (int nf = 0; nf < 4; ++nf)
      bfr[nf] = *(const bf16x8*)&Bl[cur][(wn * 64 + nf * 16 + c) * 32 + g * 8];
    __builtin_amdgcn_s_setprio(1);
#pragma unroll
    for (int mf = 0; mf < 4; ++mf)
#pragma unroll
      for (int nf = 0; nf < 4; ++nf)
        acc[mf][nf] = __builtin_amdgcn_mfma_f32_16x16x32_bf16(
            af[mf], bfr[nf], acc[mf][nf], 0, 0, 0);
    __builtin_amdgcn_s_setprio(0);
  }

  if (MODE == 0) {
    const int proj = n0 >> 9;  // 0=q,1=k,2=v
    const float* bias = proj == 0 ? b0 : (proj == 1 ? b1 : b2);
    unsigned short* dst01 = proj == 0 ? qo : ko;
    // q pre-scale folds 1/sqrt(64) AND log2(e) so attention can use exp2
    const float scale = proj == 0 ? 0.18033688011112042f : 1.0f;
#pragma unroll
    for (int nf = 0; nf < 4; ++nf) {
      const int col5 = (n0 + wn * 64 + nf * 16 + c) & 511;
      const int h = col5 >> 6, o = col5 & 63;
      const float bb = bias[col5];
#pragma unroll
      for (int mf = 0; mf < 4; ++mf) {
#pragma unroll
        for (int r = 0; r < 4; ++r) {
          const int m = m0 + wm * 64 + mf * 16 + g * 4 + r;
          const int b = m >> 12, s = m & 4095;
          const unsigned short hb = f2bf((acc[mf][nf][r] + bb) * scale);
          if (proj < 2)
            dst01[((size_t)((b * NH + h) * NS + s)) * 64 + o] = hb;
          else
            vo[((size_t)((b * NH + h) * 64 + o)) * NS + s] = hb;
        }
      }
    }
  } else {
#pragma unroll
    for (int nf = 0; nf < 4; ++nf) {
      const int col = n0 + wn * 64 + nf * 16 + c;
      const float bb = b0[col];
#pragma unroll
      for (int mf = 0; mf < 4; ++mf) {
#pragma unroll
        for (int r = 0; r < 4; ++r) {
          const int m = m0 + wm * 64 + mf * 16 + g * 4 + r;
          fo[(size_t)m * 512 + col] = acc[mf][nf][r] + bb;
        }
      }
    }
  }
}

// ------- flash attention v16: r15 body + race-free 3-buffer ring ----------
// Staging = r9/r13's stable scheme (absmax 4.88e-4 both times): 2 tiles in
// flight, counted vmcnt(4) in-loop (tile t's 4 loads landed, t+1's stay in
// flight), vmcnt(0) only at the last iteration; ISSUE(t+2) after the barrier
// overwrites buf[(t-1)%3], whose readers finished before this barrier.
__global__ __launch_bounds__(256, 2) void attn_kernel(
    const unsigned short* __restrict__ q,     // [bh][s][64] (pre-scaled)
    const unsigned short* __restrict__ k,     // [bh][s][64]
    const unsigned short* __restrict__ vt,    // [bh][64][s]
    unsigned short* __restrict__ cc)          // [b][s][512]
{
  union SMemU {
    struct { unsigned short Kl[3][4096]; unsigned short Vl[3][4096]; } kv;
    unsigned short Ol[4][32][68];  // epilogue transpose (K/V dead by then)
  };
  __shared__ SMemU sm;
  const int t = threadIdx.x;
  const int w = t >> 6, lane = t & 63;
  const int col = lane & 31, hi = lane >> 5;
  const int bh = blockIdx.y;
  const int b = bh >> 3, h = bh & 7;
  const int q0 = blockIdx.x * 128 + w * 32;  // this wave's 32 q-rows

  const unsigned short* qh = q + (size_t)bh * NS * 64;
  const unsigned short* kh = k + (size_t)bh * NS * 64;
  const unsigned short* vh = vt + (size_t)bh * 64 * NS;

  // Q as B-operand: lane qrow = q0 + col, d = c*16 + hi*8 + j
  bf16x8 qf[4];
#pragma unroll
  for (int c = 0; c < 4; ++c)
    qf[c] = *(const bf16x8*)&qh[(size_t)(q0 + col) * 64 + c * 16 + hi * 8];

  // DMA staging: pre-swizzled global source + linear LDS dest keeps the
  // proven XOR layout: LDS[row][ch] = G[row][ch ^ (row&7)].
  const int rl = lane >> 3, chn = lane & 7;
  const int lk = rl * 64 + ((chn ^ (rl & 7)) << 3);   // shorts
  const int lv = rl * NS + ((chn ^ (rl & 7)) << 3);   // shorts

  auto ISSUE = [&](int tile, int bi) {
    const unsigned short* gk = kh + (size_t)(tile * 64 + w * 16) * 64;
    const unsigned short* gv = vh + (size_t)(w * 16) * NS + tile * 64;
    gload_lds16(gk + lk, &sm.kv.Kl[bi][w * 1024]);
    gload_lds16(gk + lk + 512, &sm.kv.Kl[bi][w * 1024 + 512]);
    gload_lds16(gv + lv, &sm.kv.Vl[bi][w * 1024]);
    gload_lds16(gv + lv + 8 * NS, &sm.kv.Vl[bi][w * 1024 + 512]);
  };

  f32x16 ot0, ot1;
#pragma unroll
  for (int r = 0; r < 16; ++r) { ot0[r] = 0.f; ot1[r] = 0.f; }
  float l_ = 0.f;

  const int NT = NS / 64;  // 64 tiles

  // prologue: 2 tiles in flight
  ISSUE(0, 0);
  ISSUE(1, 1);

  int cur = 0;
  for (int it = 0; it < NT; ++it) {
    // tile `it`'s 4 loads are the OLDEST outstanding; tile it+1's 4 stay
    // in flight (counted vmcnt) except at the final iteration.
    if (it + 1 < NT)
      asm volatile("s_waitcnt vmcnt(4)" ::: "memory");
    else
      asm volatile("s_waitcnt vmcnt(0)" ::: "memory");
    __builtin_amdgcn_s_barrier();
    __builtin_amdgcn_sched_barrier(0);
    if (it + 2 < NT) {
      int b2 = cur + 2;
      if (b2 >= 3) b2 -= 3;
      ISSUE(it + 2, b2);  // overwrites buf[(it-1)%3]: readers done (barrier)
    }

    // ---- K fragments (8 x ds_read_b128), QK ----
    bf16x8 kfr[2][4];
#pragma unroll
    for (int c = 0; c < 4; ++c) {
      const int cidx = (((2 * c + hi) ^ (col & 7)) << 3);
      kfr[0][c] = *(const bf16x8*)&sm.kv.Kl[cur][col * 64 + cidx];
      kfr[1][c] = *(const bf16x8*)&sm.kv.Kl[cur][(col + 32) * 64 + cidx];
    }
    f32x16 p0, p1;
#pragma unroll
    for (int r = 0; r < 16; ++r) { p0[r] = 0.f; p1[r] = 0.f; }
    __builtin_amdgcn_s_setprio(1);
#pragma unroll
    for (int c = 0; c < 4; ++c) {
      p0 = __builtin_amdgcn_mfma_f32_32x32x16_bf16(kfr[0][c], qf[c], p0, 0, 0, 0);
      p1 = __builtin_amdgcn_mfma_f32_32x32x16_bf16(kfr[1][c], qf[c], p1, 0, 0, 0);
    }
    __builtin_amdgcn_s_setprio(0);

    // ---- V fragments issued early (ds latency hides under softmax) ----
    bf16x8 vfr[2][4];
#pragma unroll
    for (int ks = 0; ks < 4; ++ks) {
      const int cidx = (((2 * ks + hi) ^ (col & 7)) << 3);
      vfr[0][ks] = *(const bf16x8*)&sm.kv.Vl[cur][col * 64 + cidx];
      vfr[1][ks] = *(const bf16x8*)&sm.kv.Vl[cur][(col + 32) * 64 + cidx];
    }

    // ---- shift-0 softmax: exp, row-sum, P->bf16 fragments in-register ----
#pragma unroll
    for (int r = 0; r < 16; ++r) {
      p0[r] = exp2_hw(p0[r]);
      p1[r] = exp2_hw(p1[r]);
    }
    {
      float s[8];
#pragma unroll
      for (int r = 0; r < 8; ++r)
        s[r] = (p0[r] + p0[r + 8]) + (p1[r] + p1[r + 8]);
      float rs =
          ((s[0] + s[1]) + (s[2] + s[3])) + ((s[4] + s[5]) + (s[6] + s[7]));
      rs += __shfl_xor(rs, 32, 64);
      l_ += rs;
    }
    bf16x8 pb[4];
    {
      unsigned g0[8], g1[8];
#pragma unroll
      for (int gg = 0; gg < 8; ++gg) {
        g0[gg] = cvtpk(p0[2 * gg], p0[2 * gg + 1]);
        g1[gg] = cvtpk(p1[2 * gg], p1[2 * gg + 1]);
      }
      unsigned a1, b1, c1, d1;
      a1 = g0[0]; b1 = g0[2]; swap32(a1, b1);
      c1 = g0[1]; d1 = g0[3]; swap32(c1, d1);
      pb[0] = mkfrag(a1, c1, b1, d1);
      a1 = g0[4]; b1 = g0[6]; swap32(a1, b1);
      c1 = g0[5]; d1 = g0[7]; swap32(c1, d1);
      pb[1] = mkfrag(a1, c1, b1, d1);
      a1 = g1[0]; b1 = g1[2]; swap32(a1, b1);
      c1 = g1[1]; d1 = g1[3]; swap32(c1, d1);
      pb[2] = mkfrag(a1, c1, b1, d1);
      a1 = g1[4]; b1 = g1[6]; swap32(a1, b1);
      c1 = g1[5]; d1 = g1[7]; swap32(c1, d1);
      pb[3] = mkfrag(a1, c1, b1, d1);
    }

    // ---- PV ----
    __builtin_amdgcn_s_setprio(1);
#pragma unroll
    for (int ks = 0; ks < 4; ++ks) {
      ot0 = __builtin_amdgcn_mfma_f32_32x32x16_bf16(vfr[0][ks], pb[ks], ot0, 0, 0, 0);
      ot1 = __builtin_amdgcn_mfma_f32_32x32x16_bf16(vfr[1][ks], pb[ks], ot1, 0, 0, 0);
    }
    __builtin_amdgcn_s_setprio(0);

    cur = (cur + 1 == 3) ? 0 : cur + 1;
  }

  __syncthreads();  // all waves done with K/V LDS before Ol-union writes

  // ---- epilogue: normalize + transpose via LDS, coalesced store ----
  const float inv = 1.0f / l_;
#pragma unroll
  for (int r = 0; r < 16; ++r) {
    const int dvb = (r & 3) + 8 * (r >> 2) + 4 * hi;
    sm.Ol[w][col][dvb] = f2bf(ot0[r] * inv);
    sm.Ol[w][col][dvb + 32] = f2bf(ot1[r] * inv);
  }
  asm volatile("s_waitcnt lgkmcnt(0)" ::: "memory");
  const int row = lane >> 1;
#pragma unroll
  for (int p = 0; p < 4; ++p) {
    const int chunk = (lane & 1) + 2 * p;
    bf16x8 vv = *(const bf16x8*)&sm.Ol[w][row][chunk * 8];
    *(bf16x8*)&cc[((size_t)(b * NS + q0 + row)) * 512 + h * 64 + chunk * 8] = vv;
  }
}

extern "C" void kernel_launch(void* const* d_in, const int* in_sizes, int n_in,
                              void* d_out, int out_size, void* d_ws, size_t ws_size,
                              hipStream_t stream) {
  const float* x  = (const float*)d_in[0];
  const float* Wq = (const float*)d_in[1];
  const float* bq = (const float*)d_in[2];
  const float* Wk = (const float*)d_in[3];
  const float* bk = (const float*)d_in[4];
  const float* Wv = (const float*)d_in[5];
  const float* bv = (const float*)d_in[6];
  const float* Wo = (const float*)d_in[7];
  const float* bo = (const float*)d_in[8];

  unsigned char* ws = (unsigned char*)d_ws;
  unsigned short* x_bf = (unsigned short*)(ws);              // 8 MB [8192][512]
  unsigned short* w3   = (unsigned short*)(ws + 8388608);    // 1.5 MB
  unsigned short* wo_t = (unsigned short*)(ws + 9961472);    // 0.5 MB
  unsigned short* qb   = (unsigned short*)(ws + 10485760);   // 8 MB [16][4096][64]
  unsigned short* kb   = (unsigned short*)(ws + 18874368);   // 8 MB
  unsigned short* vb   = (unsigned short*)(ws + 27262976);   // 8 MB [16][64][4096]
  unsigned short* cc   = x_bf;  // reuse: x_bf dead after QKV GEMM

  pack_kernel<<<8192, 256, 0, stream>>>(x, Wq, Wk, Wv, Wo, x_bf, w3, wo_t);
  gemm_bt<0><<<dim3(64, 12), 256, 0, stream>>>(x_bf, w3, bq, bk, bv, qb, kb, vb,
                                               nullptr);
  attn_kernel<<<dim3(32, 16), 256, 0, stream>>>(qb, kb, vb, cc);
  gemm_bt<1><<<dim3(64, 4), 256, 0, stream>>>(cc, wo_t, bo, nullptr, nullptr,
                                              nullptr, nullptr, nullptr,
                                              (float*)d_out);
}